// Round 2
// baseline (2585.400 us; speedup 1.0000x reference)
//
#include <hip/hip_runtime.h>
#include <math.h>

#define B_  2
#define T_  4096
#define D_  1024
#define H_  16
#define BH_ 32

// ---------------------------------------------------------------------------
// DPP quad-perm butterfly adds (xor-1, xor-2 within a 4-lane quad).
// Much lower latency than ds_swizzle-based __shfl_xor on the scan's
// serial critical path.
// ---------------------------------------------------------------------------
__device__ __forceinline__ float dpp_xor1_add(float v) {
  int s = __builtin_amdgcn_update_dpp(0, __float_as_int(v), 0xB1, 0xF, 0xF, true);
  return v + __int_as_float(s);
}
__device__ __forceinline__ float dpp_xor2_add(float v) {
  int s = __builtin_amdgcn_update_dpp(0, __float_as_int(v), 0x4E, 0xF, 0xF, true);
  return v + __int_as_float(s);
}

// ---------------------------------------------------------------------------
// Generic f32 tiled GEMM: C[M,N] = A[M,K] @ B[K,N], optional activation.
// BM=128, BN=128, BK=16, 256 threads, 8x8 micro-tile per thread.
// ACT: 0=none, 1=silu, 2=sigmoid
// ---------------------------------------------------------------------------
template<int ACT>
__global__ __launch_bounds__(256) void gemm_f32(const float* __restrict__ A,
    const float* __restrict__ Bm, float* __restrict__ C, int M, int N, int K)
{
  __shared__ float As[16][128];
  __shared__ float Bs[16][128];
  const int bm  = blockIdx.y * 128;
  const int bn  = blockIdx.x * 128;
  const int tid = threadIdx.x;
  const int tx  = tid & 15;   // 16 col-threads * 8 cols = 128
  const int ty  = tid >> 4;   // 16 row-threads * 8 rows = 128

  float acc[8][8];
  #pragma unroll
  for (int i = 0; i < 8; ++i)
    #pragma unroll
    for (int j = 0; j < 8; ++j) acc[i][j] = 0.f;

  const int r  = tid >> 2;        // 0..63 (A row within half-tile)
  const int kq = (tid & 3) * 4;   // 0,4,8,12 (k quad)
  const int bk = tid >> 4;        // 0..15 (B tile row)
  const int nq = (tid & 15) * 8;  // B tile col base

  for (int k0 = 0; k0 < K; k0 += 16) {
    // A tile 128x16, transposed into LDS As[k][m]
    float4 a0 = *(const float4*)(A + (size_t)(bm + r)      * K + k0 + kq);
    float4 a1 = *(const float4*)(A + (size_t)(bm + 64 + r) * K + k0 + kq);
    As[kq+0][r]    = a0.x; As[kq+1][r]    = a0.y; As[kq+2][r]    = a0.z; As[kq+3][r]    = a0.w;
    As[kq+0][64+r] = a1.x; As[kq+1][64+r] = a1.y; As[kq+2][64+r] = a1.z; As[kq+3][64+r] = a1.w;
    // B tile 16x128
    *(float4*)&Bs[bk][nq]   = *(const float4*)(Bm + (size_t)(k0 + bk) * N + bn + nq);
    *(float4*)&Bs[bk][nq+4] = *(const float4*)(Bm + (size_t)(k0 + bk) * N + bn + nq + 4);
    __syncthreads();
    #pragma unroll
    for (int kk = 0; kk < 16; ++kk) {
      float a[8], b[8];
      *(float4*)&a[0] = *(float4*)&As[kk][ty*8];
      *(float4*)&a[4] = *(float4*)&As[kk][ty*8+4];
      *(float4*)&b[0] = *(float4*)&Bs[kk][tx*8];
      *(float4*)&b[4] = *(float4*)&Bs[kk][tx*8+4];
      #pragma unroll
      for (int i = 0; i < 8; ++i)
        #pragma unroll
        for (int j = 0; j < 8; ++j)
          acc[i][j] = fmaf(a[i], b[j], acc[i][j]);
    }
    __syncthreads();
  }

  #pragma unroll
  for (int i = 0; i < 8; ++i) {
    float o[8];
    #pragma unroll
    for (int j = 0; j < 8; ++j) {
      float v = acc[i][j];
      if (ACT == 1)      v = v / (1.f + __expf(-v));   // silu
      else if (ACT == 2) v = 1.f / (1.f + __expf(-v)); // sigmoid
      o[j] = v;
    }
    float* cp = C + (size_t)(bm + ty*8 + i) * N + bn + tx*8;
    *(float4*)cp       = *(float4*)&o[0];
    *(float4*)(cp + 4) = *(float4*)&o[4];
  }
}

// ---------------------------------------------------------------------------
// Causal depthwise conv (K=4) + bias + SiLU, reshaped to heads [BH,T,64].
// Optional L2 norm across the 64 head channels (one wave = 64 channels).
// grid: (T/16, BH), block: 64
// ---------------------------------------------------------------------------
template<bool L2N>
__global__ __launch_bounds__(64) void conv_head(const float* __restrict__ xin, // [B,T,D]
    const float* __restrict__ w,    // [H*64, 4]
    const float* __restrict__ bias, // [H*64]
    float* __restrict__ out)        // [BH,T,64]
{
  const int bh = blockIdx.y;
  const int b  = bh >> 4, h = bh & 15;
  const int t0 = blockIdx.x * 16;
  const int c  = threadIdx.x;
  const int ch = h*64 + c;
  const float w0 = w[ch*4+0], w1 = w[ch*4+1], w2 = w[ch*4+2], w3 = w[ch*4+3];
  const float bs = bias[ch];
  const float* xp = xin + ((size_t)b*T_ + t0)*D_ + ch;
  float xm3 = (t0 >= 3) ? xp[-3*D_] : 0.f;
  float xm2 = (t0 >= 2) ? xp[-2*D_] : 0.f;
  float xm1 = (t0 >= 1) ? xp[-1*D_] : 0.f;
  float* op = out + ((size_t)bh*T_ + t0)*64 + c;
  for (int tt = 0; tt < 16; ++tt) {
    float xc = xp[(size_t)tt * D_];
    float v  = fmaf(w0, xm3, fmaf(w1, xm2, fmaf(w2, xm1, fmaf(w3, xc, bs))));
    v = v / (1.f + __expf(-v));   // silu
    if (L2N) {
      float ss = v*v;
      #pragma unroll
      for (int off = 32; off > 0; off >>= 1) ss += __shfl_xor(ss, off, 64);
      v = v / fmaxf(sqrtf(ss), 1e-6f);
    }
    op[tt*64] = v;
    xm3 = xm2; xm2 = xm1; xm1 = xc;
  }
}

// ---------------------------------------------------------------------------
// alpha/beta gates: alpha = clip(sigmoid(x@Wa+ba),0.1,1), beta = min(sig,1)
// one block per (b,t) row; 32 outputs (16 a + 16 b) x 8 lanes each.
// ---------------------------------------------------------------------------
__global__ __launch_bounds__(256) void ab_kernel(const float* __restrict__ x,
    const float* __restrict__ Wa, const float* __restrict__ ba,
    const float* __restrict__ Wb, const float* __restrict__ bb,
    float* __restrict__ alpha, float* __restrict__ beta) // [BH,T]
{
  __shared__ float xs[1024];
  const int rrow = blockIdx.x;            // 0..8191
  const int b = rrow >> 12, t = rrow & 4095;
  const int tid = threadIdx.x;
  ((float4*)xs)[tid] = ((const float4*)(x + (size_t)rrow * D_))[tid];
  __syncthreads();
  const int out = tid >> 3;   // 0..31
  const int s   = tid & 7;    // 0..7
  const bool isB = out >= 16;
  const int h = out & 15;
  const float* W = isB ? Wb : Wa;
  float acc = 0.f;
  #pragma unroll 8
  for (int m = 0; m < 128; ++m) {
    int kidx = m*8 + s;
    acc = fmaf(xs[kidx], W[kidx*16 + h], acc);
  }
  acc += __shfl_xor(acc, 1, 64);
  acc += __shfl_xor(acc, 2, 64);
  acc += __shfl_xor(acc, 4, 64);
  if (s == 0) {
    float bias = isB ? bb[h] : ba[h];
    float sg = 1.f / (1.f + __expf(-(acc + bias)));
    int bh = b*16 + h;
    if (isB) beta [(size_t)bh*T_ + t] = fminf(sg, 1.0f);
    else     alpha[(size_t)bh*T_ + t] = fminf(fmaxf(sg, 0.1f), 1.0f);
  }
}

// ---------------------------------------------------------------------------
// Sequential gated delta-rule scan. State columns are independent:
// block = one head (bh); 256 thr = 64 cols x 4 row-groups (16 rows each).
// K/Q/V staged in LDS per 64-step chunk. Cross-lane reduces via DPP quad
// perms (critical-path latency), o-reduce off the critical path.
// ---------------------------------------------------------------------------
__global__ __launch_bounds__(256) void scan_kernel(const float* __restrict__ Q,
    const float* __restrict__ Kh, const float* __restrict__ V,
    const float* __restrict__ alpha, const float* __restrict__ beta,
    float* __restrict__ O)
{
  __shared__ float ks[64*64];
  __shared__ float qs[64*64];
  __shared__ float vs[64*64];
  __shared__ float as_[64];
  __shared__ float bs_[64];
  const int bh  = blockIdx.x;
  const int tid = threadIdx.x;
  const int j   = tid >> 2;          // state column (DV)
  const int rg  = (tid & 3) * 16;    // row-group base (DK)
  float S[16];
  #pragma unroll
  for (int m = 0; m < 16; ++m) S[m] = 0.f;
  const float* Qb = Q  + (size_t)bh * T_ * 64;
  const float* Kb = Kh + (size_t)bh * T_ * 64;
  const float* Vb = V  + (size_t)bh * T_ * 64;
  float*       Ob = O  + (size_t)bh * T_ * 64;

  for (int t0 = 0; t0 < T_; t0 += 64) {
    const float4* gq = (const float4*)(Qb + (size_t)t0 * 64);
    const float4* gk = (const float4*)(Kb + (size_t)t0 * 64);
    const float4* gv = (const float4*)(Vb + (size_t)t0 * 64);
    #pragma unroll
    for (int i = 0; i < 4; ++i) {
      ((float4*)qs)[tid + 256*i] = gq[tid + 256*i];
      ((float4*)ks)[tid + 256*i] = gk[tid + 256*i];
      ((float4*)vs)[tid + 256*i] = gv[tid + 256*i];
    }
    if (tid < 64)        as_[tid]     = alpha[(size_t)bh*T_ + t0 + tid];
    else if (tid < 128)  bs_[tid-64]  = beta [(size_t)bh*T_ + t0 + (tid-64)];
    __syncthreads();

    #pragma unroll 2
    for (int tt = 0; tt < 64; ++tt) {
      float kf[16], qf[16];
      #pragma unroll
      for (int i = 0; i < 4; ++i) {
        *(float4*)&kf[i*4] = *(const float4*)&ks[tt*64 + rg + i*4];
        *(float4*)&qf[i*4] = *(const float4*)&qs[tt*64 + rg + i*4];
      }
      const float vj = vs[tt*64 + j];
      const float a  = as_[tt];
      const float bg = bs_[tt];
      // v_hat_j = sum_i S[i][j] * k[i]  (16 rows here, then 4-lane DPP reduce)
      float vh0=0.f, vh1=0.f, vh2=0.f, vh3=0.f;
      #pragma unroll
      for (int m = 0; m < 4; ++m) {
        vh0 = fmaf(S[m],    kf[m],    vh0);
        vh1 = fmaf(S[m+4],  kf[m+4],  vh1);
        vh2 = fmaf(S[m+8],  kf[m+8],  vh2);
        vh3 = fmaf(S[m+12], kf[m+12], vh3);
      }
      float vh = (vh0+vh1) + (vh2+vh3);
      vh = dpp_xor1_add(vh);
      vh = dpp_xor2_add(vh);
      const float cc = bg * (vj - vh);     // beta * err_j
      // S update + o partial
      float o0=0.f, o1=0.f, o2=0.f, o3=0.f;
      #pragma unroll
      for (int m = 0; m < 4; ++m) {
        S[m]    = fmaf(S[m],    a, cc*kf[m]);
        S[m+4]  = fmaf(S[m+4],  a, cc*kf[m+4]);
        S[m+8]  = fmaf(S[m+8],  a, cc*kf[m+8]);
        S[m+12] = fmaf(S[m+12], a, cc*kf[m+12]);
        o0 = fmaf(S[m],    qf[m],    o0);
        o1 = fmaf(S[m+4],  qf[m+4],  o1);
        o2 = fmaf(S[m+8],  qf[m+8],  o2);
        o3 = fmaf(S[m+12], qf[m+12], o3);
      }
      float o = (o0+o1) + (o2+o3);
      o = dpp_xor1_add(o);
      o = dpp_xor2_add(o);
      if ((tid & 3) == 0) Ob[(size_t)(t0+tt)*64 + j] = o;
    }
    __syncthreads();
  }
}

// ---------------------------------------------------------------------------
// Per-head RMSNorm + sigmoid output gate; writes [B,T,H*64] layout.
// grid: (T/16, BH), block 64
// ---------------------------------------------------------------------------
__global__ __launch_bounds__(64) void rmsgate(const float* __restrict__ O,  // [BH,T,64]
    const float* __restrict__ g,    // [B,T,D] (already sigmoided)
    const float* __restrict__ rmsw, // [H,64]
    float* __restrict__ outp)       // [B,T,D]
{
  const int bh = blockIdx.y;
  const int b  = bh >> 4, h = bh & 15;
  const int t0 = blockIdx.x * 16;
  const int c  = threadIdx.x;
  const float rw = rmsw[h*64 + c];
  for (int tt = 0; tt < 16; ++tt) {
    const int t = t0 + tt;
    float o  = O[((size_t)bh*T_ + t)*64 + c];
    float ss = o*o;
    #pragma unroll
    for (int off = 32; off > 0; off >>= 1) ss += __shfl_xor(ss, off, 64);
    float r   = rsqrtf(ss * (1.f/64.f) + 1e-6f);
    float val = o * r * rw * g[((size_t)b*T_ + t)*D_ + h*64 + c];
    outp[((size_t)b*T_ + t)*D_ + h*64 + c] = val;
  }
}

// ---------------------------------------------------------------------------
// Workspace layout (floats):
//   linbuf : 8M   (serially holds q_lin, k_lin, v_lin, then g)
//   Qh     : 8M
//   Kk     : 8M
//   Vv     : 8M   (O aliases Vv: scan stages each 64-row chunk to LDS and
//                  syncs before overwriting exactly those rows)
//   g1     : 4M
//   alpha  : 128K, beta: 128K
//   gated  : aliases Qh (dead after scan)
// Total ≈ 36.5M floats ≈ 146 MB.
// ---------------------------------------------------------------------------
extern "C" void kernel_launch(void* const* d_in, const int* in_sizes, int n_in,
                              void* d_out, int out_size, void* d_ws, size_t ws_size,
                              hipStream_t stream)
{
  const float* x    = (const float*)d_in[0];
  const float* Wq   = (const float*)d_in[1];
  const float* Wk   = (const float*)d_in[2];
  const float* Wv   = (const float*)d_in[3];
  const float* Wo   = (const float*)d_in[4];
  const float* Wa   = (const float*)d_in[5];
  const float* ba   = (const float*)d_in[6];
  const float* Wb   = (const float*)d_in[7];
  const float* bb   = (const float*)d_in[8];
  const float* Wgd  = (const float*)d_in[9];
  const float* Wgu  = (const float*)d_in[10];
  const float* rmsw = (const float*)d_in[11];
  const float* qcw  = (const float*)d_in[12];
  const float* qcb  = (const float*)d_in[13];
  const float* kcw  = (const float*)d_in[14];
  const float* kcb  = (const float*)d_in[15];
  const float* vcw  = (const float*)d_in[16];
  const float* vcb  = (const float*)d_in[17];

  float* ws = (float*)d_ws;
  const size_t S0 = (size_t)8192 * 1024;
  float* linbuf = ws;               // [8192,1024] staging / later g
  float* Qh     = ws + S0;
  float* Kk     = ws + 2*S0;
  float* Vv     = ws + 3*S0;        // O aliases this
  float* g1     = ws + 4*S0;                        // [8192,512]
  float* alpha  = ws + 4*S0 + (size_t)8192*512;     // [BH,T]
  float* beta   = alpha + (size_t)BH_ * T_;

  const dim3 blk256(256);
  const dim3 gBig(8, 64);   // N=1024: 1024/128=8, M: 8192/128=64
  const dim3 gMid(4, 64);   // N=512

  // q chain
  gemm_f32<0><<<gBig, blk256, 0, stream>>>(x, Wq, linbuf, 8192, 1024, 1024);
  conv_head<true ><<<dim3(T_/16, BH_), 64, 0, stream>>>(linbuf, qcw, qcb, Qh);
  // k chain
  gemm_f32<0><<<gBig, blk256, 0, stream>>>(x, Wk, linbuf, 8192, 1024, 1024);
  conv_head<true ><<<dim3(T_/16, BH_), 64, 0, stream>>>(linbuf, kcw, kcb, Kk);
  // v chain
  gemm_f32<0><<<gBig, blk256, 0, stream>>>(x, Wv, linbuf, 8192, 1024, 1024);
  conv_head<false><<<dim3(T_/16, BH_), 64, 0, stream>>>(linbuf, vcw, vcb, Vv);
  // gates
  ab_kernel<<<8192, blk256, 0, stream>>>(x, Wa, ba, Wb, bb, alpha, beta);
  gemm_f32<1><<<gMid, blk256, 0, stream>>>(x, Wgd, g1, 8192, 512, 1024);   // silu fused
  float* g = linbuf;  // linbuf dead after conv v
  gemm_f32<2><<<gBig, blk256, 0, stream>>>(g1, Wgu, g, 8192, 1024, 512);   // sigmoid fused
  // sequential gated delta-rule scan (O aliases Vv)
  float* O = Vv;
  scan_kernel<<<BH_, blk256, 0, stream>>>(Qh, Kk, Vv, alpha, beta, O);
  // RMSNorm + gate (gated reuses Qh, dead after scan)
  float* gated = Qh;
  rmsgate<<<dim3(T_/16, BH_), 64, 0, stream>>>(O, g, rmsw, gated);
  // final projection
  gemm_f32<0><<<gBig, blk256, 0, stream>>>(gated, Wo, (float*)d_out, 8192, 1024, 1024);
}